// Round 2
// baseline (758.922 us; speedup 1.0000x reference)
//
#include <hip/hip_runtime.h>
#include <stdint.h>

#define VOCAB 50257
#define NP    50304      // padded vocab = 393*128
#define H     256
#define BS    4096       // B*S tokens
#define K2    512        // hi/lo interleaved K
#define SIB   0.0625f    // 1/sqrt(256)

typedef __attribute__((ext_vector_type(8))) _Float16 f16x8;
typedef __attribute__((ext_vector_type(4))) float f32x4;

__device__ __forceinline__ void gload_lds16(const void* g, void* l) {
  __builtin_amdgcn_global_load_lds(
      (const __attribute__((address_space(1))) void*)g,
      (__attribute__((address_space(3))) void*)l, 16, 0, 0);
}

// ---------------- sib projections: polW@sib0, polW@sib1, childW@sib0, childW@sib1
__global__ __launch_bounds__(256) void k_sib(const float* __restrict__ pol_W1,
                                             const float* __restrict__ child_W,
                                             const float* __restrict__ sib_emb,
                                             float* __restrict__ sibproj) {
  const int b = blockIdx.x;  // 0..3
  const float* Wm = (b < 2) ? pol_W1 : child_W;
  const float* v = sib_emb + (b & 1) * H;
  const int h = threadIdx.x;
  const float4* wr = (const float4*)(Wm + h * H);
  const float4* vr = (const float4*)v;
  float acc = 0.f;
  for (int i = 0; i < 64; ++i) {
    float4 w = wr[i], x = vr[i];
    acc += w.x * x.x + w.y * x.y + w.z * x.z + w.w * x.w;
  }
  sibproj[b * H + h] = acc;
}

// ---------------- out_W f32 -> interleaved f16 hi/lo (lo pre-scaled by 64)
__global__ __launch_bounds__(256) void k_conv(const float* __restrict__ W,
                                              _Float16* __restrict__ B2) {
  const int64_t nit = (int64_t)NP * 64;
  for (int64_t i = (int64_t)blockIdx.x * blockDim.x + threadIdx.x; i < nit;
       i += (int64_t)gridDim.x * blockDim.x) {
    const int v = (int)(i >> 6);
    const int h4 = ((int)i & 63) * 4;
    float4 w;
    if (v < VOCAB) w = *(const float4*)(W + (int64_t)v * H + h4);
    else w = make_float4(0.f, 0.f, 0.f, 0.f);
    float a[4] = {w.x, w.y, w.z, w.w};
    _Float16 o[8];
#pragma unroll
    for (int j = 0; j < 4; ++j) {
      _Float16 hi = (_Float16)a[j];
      float lo = (a[j] - (float)hi) * 64.f;
      o[2 * j] = hi;
      o[2 * j + 1] = (_Float16)lo;
    }
    *(f16x8*)(B2 + (int64_t)v * K2 + h4 * 2) = *(f16x8*)o;
  }
}

// ---------------- per-token tree -> pooled -> A2 (f16, dup columns: [a, a/64])
#define MATVEC(Wp, SRC, ACC)                                                      \
  do {                                                                            \
    _Pragma("unroll") for (int j = 0; j < 4; ++j)                                 \
        _Pragma("unroll") for (int tt = 0; tt < 4; ++tt) ACC[j][tt] = 0.f;        \
    _Pragma("unroll 2") for (int e4 = 0; e4 < 64; ++e4) {                         \
      float4 wv[4], sv[4];                                                        \
      _Pragma("unroll") for (int j = 0; j < 4; ++j)                               \
          wv[j] = *(const float4*)(Wp + (hg + 64 * j) * H + e4 * 4);              \
      _Pragma("unroll") for (int tt = 0; tt < 4; ++tt)                            \
          sv[tt] = *(const float4*)&SRC[tg * 4 + tt][e4 * 4];                     \
      _Pragma("unroll") for (int j = 0; j < 4; ++j)                               \
          _Pragma("unroll") for (int tt = 0; tt < 4; ++tt)                        \
              ACC[j][tt] += wv[j].x * sv[tt].x + wv[j].y * sv[tt].y +             \
                            wv[j].z * sv[tt].z + wv[j].w * sv[tt].w;              \
    }                                                                             \
  } while (0)

#define REDUCE_TO_X(slot)                                                \
  do {                                                                   \
    const int rt = tid >> 4, rl = tid & 15;                              \
    float part = 0.f;                                                    \
    _Pragma("unroll") for (int i = 0; i < 16; ++i) part +=               \
        ZW[rt][rl + 16 * i];                                             \
    part += __shfl_xor(part, 1, 16);                                     \
    part += __shfl_xor(part, 2, 16);                                     \
    part += __shfl_xor(part, 4, 16);                                     \
    part += __shfl_xor(part, 8, 16);                                     \
    if (rl == 0) X[slot][rt] = part + b2;                                \
  } while (0)

__global__ __launch_bounds__(256) void k_pooled(
    const int* __restrict__ tokens, const float* __restrict__ emb,
    const float* __restrict__ proj_W, const float* __restrict__ proj_b,
    const float* __restrict__ child_W, const float* __restrict__ child_b,
    const float* __restrict__ sib_emb, const float* __restrict__ depth_emb,
    const float* __restrict__ pol_W1, const float* __restrict__ pol_b1,
    const float* __restrict__ pol_w2, const float* __restrict__ pol_b2,
    const float* __restrict__ sibproj, _Float16* __restrict__ A2) {
  __shared__ float IN[16][256];
  __shared__ float H0[16][256];
  __shared__ float B0s[16][256];
  __shared__ float ZW[16][264];
  __shared__ float X[3][16];
  __shared__ int TOK[16];
  const int tid = threadIdx.x;
  const int hg = tid & 63;   // h = hg + 64*j
  const int tg = tid >> 6;   // tokens tg*4 .. tg*4+3
  const int t0 = blockIdx.x * 16;
  const float b2 = pol_b2[0];

  float sibs[4];
#pragma unroll
  for (int j = 0; j < 4; ++j) {
    const int hj = hg + 64 * j;
    sibs[j] = SIB * (sib_emb[hj] + sib_emb[H + hj]);
  }

  if (tid < 16) TOK[tid] = tokens[t0 + tid];
  __syncthreads();
  for (int t = 0; t < 16; ++t) IN[t][tid] = emb[(int64_t)TOK[t] * H + tid];
  __syncthreads();

  float acc[4][4], sum[4][4];

  // h0 = proj_W @ emb + proj_b
  MATVEC(proj_W, IN, acc);
#pragma unroll
  for (int j = 0; j < 4; ++j) {
    const int hj = hg + 64 * j;
    const float pb = proj_b[hj];
#pragma unroll
    for (int tt = 0; tt < 4; ++tt) {
      const float h0v = acc[j][tt] + pb;
      H0[tg * 4 + tt][hj] = h0v;
      sum[j][tt] = h0v;
    }
  }
  __syncthreads();

  // depth-0 policy
  MATVEC(pol_W1, H0, acc);
#pragma unroll
  for (int j = 0; j < 4; ++j) {
    const int hj = hg + 64 * j;
    const float pb1 = pol_b1[hj], de0 = depth_emb[hj], w2 = pol_w2[hj];
#pragma unroll
    for (int tt = 0; tt < 4; ++tt) {
      const float z = tanhf(acc[j][tt] + pb1 + de0);
      ZW[tg * 4 + tt][hj] = z * w2;
    }
  }
  __syncthreads();
  REDUCE_TO_X(0);
  __syncthreads();

  // depth-0 children base
  MATVEC(child_W, H0, acc);
#pragma unroll
  for (int j = 0; j < 4; ++j) {
    const int hj = hg + 64 * j;
    const float cb = child_b[hj];
#pragma unroll
    for (int tt = 0; tt < 4; ++tt) {
      const float base0 = tanhf(acc[j][tt] + cb);
      B0s[tg * 4 + tt][hj] = base0;
      const float g0 = (X[0][tg * 4 + tt] >= 0.f) ? 1.f : 0.f;
      sum[j][tt] += g0 * (2.f * base0 + sibs[j]);
    }
  }
  __syncthreads();

  // depth-1 policy: polW@base (+ precomputed polW@sib_k)
  float accP[4][4];
  MATVEC(pol_W1, B0s, accP);
#pragma unroll
  for (int k = 0; k < 2; ++k) {
#pragma unroll
    for (int j = 0; j < 4; ++j) {
      const int hj = hg + 64 * j;
      const float pb1 = pol_b1[hj], de1 = depth_emb[H + hj], w2 = pol_w2[hj];
      const float ps = sibproj[k * H + hj];
#pragma unroll
      for (int tt = 0; tt < 4; ++tt) {
        const float z = tanhf(accP[j][tt] + SIB * ps + pb1 + de1);
        ZW[tg * 4 + tt][hj] = z * w2;
      }
    }
    __syncthreads();
    if (k == 0) REDUCE_TO_X(1); else REDUCE_TO_X(2);
    __syncthreads();
  }

  // depth-1 children base + final pooled
  MATVEC(child_W, B0s, acc);
#pragma unroll
  for (int j = 0; j < 4; ++j) {
    const int hj = hg + 64 * j;
    const float cb = child_b[hj];
    const float cs0 = sibproj[2 * H + hj], cs1 = sibproj[3 * H + hj];
#pragma unroll
    for (int tt = 0; tt < 4; ++tt) {
      const int t = tg * 4 + tt;
      const float g0 = (X[0][t] >= 0.f) ? 1.f : 0.f;
      const float m0 = (g0 > 0.f && X[1][t] >= 0.f) ? 1.f : 0.f;
      const float m1 = (g0 > 0.f && X[2][t] >= 0.f) ? 1.f : 0.f;
      const float bk0 = tanhf(acc[j][tt] + SIB * cs0 + cb);
      const float bk1 = tanhf(acc[j][tt] + SIB * cs1 + cb);
      float s = sum[j][tt] + m0 * (2.f * bk0 + sibs[j]) + m1 * (2.f * bk1 + sibs[j]);
      const float cnt = 1.f + 2.f * g0 + 2.f * (m0 + m1);
      const float pooled = s / (cnt + 1e-8f);
      union { _Float16 hh[2]; uint32_t u; } pk;
      pk.hh[0] = (_Float16)pooled;
      pk.hh[1] = (_Float16)(pooled * 0.015625f);  // matches 64x-scaled lo plane
      *(uint32_t*)(A2 + (int64_t)(t0 + t) * K2 + 2 * hj) = pk.u;
    }
  }
}

// ---------------- big GEMM: C[4096][50257] = A2[4096][512] * B2[50304][512]^T + out_b
// Grid: 1D, 12576 blocks. XCD-chunked, n-outer / m-inner for L2 reuse.
__global__ __launch_bounds__(256) void k_gemm(const _Float16* __restrict__ A2,
                                              const _Float16* __restrict__ B2,
                                              const float* __restrict__ out_b,
                                              float* __restrict__ C) {
  __shared__ _Float16 At[128 * 32];
  __shared__ _Float16 Bt[128 * 32];
  const int tid = threadIdx.x;
  const int lane = tid & 63;
  const int w = tid >> 6;
  // bijective XCD chunking: 12576 = 8 * 1572; idx runs n-outer, m-inner
  const int wg = blockIdx.x;
  const int idx = (wg & 7) * 1572 + (wg >> 3);
  const int m0 = (idx & 31) * 128;
  const int n0 = (idx >> 5) * 128;
  f32x4 acc[4][4] = {};
  // staging: lane l -> LDS row r=l>>2, granule gl=l&3 (linear dest);
  // source granule pre-swizzled: gs = gl ^ (r&3)  (rule #21: swizzle both sides)
  const int r = lane >> 2;
  const int gs = (lane & 3) ^ (r & 3);
  const _Float16* gA = A2 + (int64_t)(m0 + w * 32 + r) * K2 + gs * 8;
  const _Float16* gB = B2 + (int64_t)(n0 + w * 32 + r) * K2 + gs * 8;
  _Float16* lA = At + (w * 32) * 32;
  _Float16* lB = Bt + (w * 32) * 32;
  const int fr = lane & 15;
  const int g = lane >> 4;                  // K-quarter
  const int sw = (g ^ (fr & 3)) * 8;        // swizzled granule offset for reads
  const int am = (w >> 1) * 64;
  const int bn = (w & 1) * 64;

  for (int ks = 0; ks < 16; ++ks) {
    const int k0 = ks * 32;
    gload_lds16(gA + k0, lA);
    gload_lds16(gA + 16 * K2 + k0, lA + 16 * 32);
    gload_lds16(gB + k0, lB);
    gload_lds16(gB + 16 * K2 + k0, lB + 16 * 32);
    __syncthreads();
    f16x8 af[4], bf[4];
#pragma unroll
    for (int i = 0; i < 4; ++i)
      af[i] = *(const f16x8*)(At + (am + i * 16 + fr) * 32 + sw);
#pragma unroll
    for (int i = 0; i < 4; ++i)
      bf[i] = *(const f16x8*)(Bt + (bn + i * 16 + fr) * 32 + sw);
#pragma unroll
    for (int i = 0; i < 4; ++i)
#pragma unroll
      for (int j = 0; j < 4; ++j)
        acc[i][j] = __builtin_amdgcn_mfma_f32_16x16x32_f16(af[i], bf[j], acc[i][j], 0, 0, 0);
    __syncthreads();
  }

#pragma unroll
  for (int j = 0; j < 4; ++j) {
    const int gn = n0 + bn + j * 16 + fr;
    if (gn < VOCAB) {
      const float bias = out_b[gn];
#pragma unroll
      for (int i = 0; i < 4; ++i) {
        const int gm = m0 + am + i * 16 + (lane >> 4) * 4;
#pragma unroll
        for (int r2 = 0; r2 < 4; ++r2)
          C[(int64_t)(gm + r2) * VOCAB + gn] = acc[i][j][r2] + bias;
      }
    }
  }
}

extern "C" void kernel_launch(void* const* d_in, const int* in_sizes, int n_in,
                              void* d_out, int out_size, void* d_ws, size_t ws_size,
                              hipStream_t stream) {
  const int* tokens = (const int*)d_in[0];
  const float* embedding = (const float*)d_in[1];
  const float* proj_W = (const float*)d_in[2];
  const float* proj_b = (const float*)d_in[3];
  const float* child_W = (const float*)d_in[4];
  const float* child_b = (const float*)d_in[5];
  const float* sib_emb = (const float*)d_in[6];
  const float* depth_emb = (const float*)d_in[7];
  const float* pol_W1 = (const float*)d_in[8];
  const float* pol_b1 = (const float*)d_in[9];
  const float* pol_w2 = (const float*)d_in[10];
  const float* pol_b2 = (const float*)d_in[11];
  const float* out_W = (const float*)d_in[12];
  const float* out_b = (const float*)d_in[13];
  float* C = (float*)d_out;
  char* ws = (char*)d_ws;
  _Float16* B2 = (_Float16*)ws;                              // 50304*512*2 = 51,511,296 B
  _Float16* A2 = (_Float16*)(ws + 51511296);                 // 4096*512*2  =  4,194,304 B
  float* sibproj = (float*)(ws + 51511296 + 4194304);        // 4*256*4 = 4 KB

  k_sib<<<4, 256, 0, stream>>>(pol_W1, child_W, sib_emb, sibproj);
  k_conv<<<2048, 256, 0, stream>>>(out_W, B2);
  k_pooled<<<256, 256, 0, stream>>>(tokens, embedding, proj_W, proj_b, child_W,
                                    child_b, sib_emb, depth_emb, pol_W1, pol_b1,
                                    pol_w2, pol_b2, sibproj, A2);
  k_gemm<<<12576, 256, 0, stream>>>(A2, B2, out_b, C);
}

// Round 4
// 660.315 us; speedup vs baseline: 1.1493x; 1.1493x over previous
//
#include <hip/hip_runtime.h>
#include <stdint.h>

#define VOCAB 50257
#define NP    50304      // padded vocab = 393*128
#define H     256
#define BS    4096       // B*S tokens
#define K2    512        // hi/lo interleaved K
#define SIB   0.0625f    // 1/sqrt(256)

typedef __attribute__((ext_vector_type(8))) _Float16 f16x8;
typedef __attribute__((ext_vector_type(4))) float f32x4;

__device__ __forceinline__ void gload_lds16(const void* g, void* l) {
  __builtin_amdgcn_global_load_lds(
      (const __attribute__((address_space(1))) void*)g,
      (__attribute__((address_space(3))) void*)l, 16, 0, 0);
}

// ---------------- sib projections: polW@sib0, polW@sib1, childW@sib0, childW@sib1
__global__ __launch_bounds__(256) void k_sib(const float* __restrict__ pol_W1,
                                             const float* __restrict__ child_W,
                                             const float* __restrict__ sib_emb,
                                             float* __restrict__ sibproj) {
  const int b = blockIdx.x;  // 0..3
  const float* Wm = (b < 2) ? pol_W1 : child_W;
  const float* v = sib_emb + (b & 1) * H;
  const int h = threadIdx.x;
  const float4* wr = (const float4*)(Wm + h * H);
  const float4* vr = (const float4*)v;
  float acc = 0.f;
  for (int i = 0; i < 64; ++i) {
    float4 w = wr[i], x = vr[i];
    acc += w.x * x.x + w.y * x.y + w.z * x.z + w.w * x.w;
  }
  sibproj[b * H + h] = acc;
}

// ---------------- out_W f32 -> interleaved f16 hi/lo (lo pre-scaled by 64)
__global__ __launch_bounds__(256) void k_conv(const float* __restrict__ W,
                                              _Float16* __restrict__ B2) {
  const int64_t nit = (int64_t)NP * 64;
  for (int64_t i = (int64_t)blockIdx.x * blockDim.x + threadIdx.x; i < nit;
       i += (int64_t)gridDim.x * blockDim.x) {
    const int v = (int)(i >> 6);
    const int h4 = ((int)i & 63) * 4;
    float4 w;
    if (v < VOCAB) w = *(const float4*)(W + (int64_t)v * H + h4);
    else w = make_float4(0.f, 0.f, 0.f, 0.f);
    float a[4] = {w.x, w.y, w.z, w.w};
    _Float16 o[8];
#pragma unroll
    for (int j = 0; j < 4; ++j) {
      _Float16 hi = (_Float16)a[j];
      float lo = (a[j] - (float)hi) * 64.f;
      o[2 * j] = hi;
      o[2 * j + 1] = (_Float16)lo;
    }
    *(f16x8*)(B2 + (int64_t)v * K2 + h4 * 2) = *(f16x8*)o;
  }
}

// ---------------- per-token tree -> pooled -> A2 (f16, dup columns: [a, a/64])
#define MATVEC(Wp, SRC, ACC)                                                      \
  do {                                                                            \
    _Pragma("unroll") for (int j = 0; j < 4; ++j)                                 \
        _Pragma("unroll") for (int tt = 0; tt < 4; ++tt) ACC[j][tt] = 0.f;        \
    _Pragma("unroll 2") for (int e4 = 0; e4 < 64; ++e4) {                         \
      float4 wv[4], sv[4];                                                        \
      _Pragma("unroll") for (int j = 0; j < 4; ++j)                               \
          wv[j] = *(const float4*)(Wp + (hg + 64 * j) * H + e4 * 4);              \
      _Pragma("unroll") for (int tt = 0; tt < 4; ++tt)                            \
          sv[tt] = *(const float4*)&SRC[tg * 4 + tt][e4 * 4];                     \
      _Pragma("unroll") for (int j = 0; j < 4; ++j)                               \
          _Pragma("unroll") for (int tt = 0; tt < 4; ++tt)                        \
              ACC[j][tt] += wv[j].x * sv[tt].x + wv[j].y * sv[tt].y +             \
                            wv[j].z * sv[tt].z + wv[j].w * sv[tt].w;              \
    }                                                                             \
  } while (0)

#define REDUCE_TO_X(slot)                                                \
  do {                                                                   \
    const int rt = tid >> 4, rl = tid & 15;                              \
    float part = 0.f;                                                    \
    _Pragma("unroll") for (int i = 0; i < 16; ++i) part +=               \
        ZW[rt][rl + 16 * i];                                             \
    part += __shfl_xor(part, 1, 16);                                     \
    part += __shfl_xor(part, 2, 16);                                     \
    part += __shfl_xor(part, 4, 16);                                     \
    part += __shfl_xor(part, 8, 16);                                     \
    if (rl == 0) X[slot][rt] = part + b2;                                \
  } while (0)

__global__ __launch_bounds__(256) void k_pooled(
    const int* __restrict__ tokens, const float* __restrict__ emb,
    const float* __restrict__ proj_W, const float* __restrict__ proj_b,
    const float* __restrict__ child_W, const float* __restrict__ child_b,
    const float* __restrict__ sib_emb, const float* __restrict__ depth_emb,
    const float* __restrict__ pol_W1, const float* __restrict__ pol_b1,
    const float* __restrict__ pol_w2, const float* __restrict__ pol_b2,
    const float* __restrict__ sibproj, _Float16* __restrict__ A2) {
  __shared__ float IN[16][256];
  __shared__ float H0[16][256];
  __shared__ float B0s[16][256];
  __shared__ float ZW[16][264];
  __shared__ float X[3][16];
  __shared__ int TOK[16];
  const int tid = threadIdx.x;
  const int hg = tid & 63;   // h = hg + 64*j
  const int tg = tid >> 6;   // tokens tg*4 .. tg*4+3
  const int t0 = blockIdx.x * 16;
  const float b2 = pol_b2[0];

  float sibs[4];
#pragma unroll
  for (int j = 0; j < 4; ++j) {
    const int hj = hg + 64 * j;
    sibs[j] = SIB * (sib_emb[hj] + sib_emb[H + hj]);
  }

  if (tid < 16) TOK[tid] = tokens[t0 + tid];
  __syncthreads();
  for (int t = 0; t < 16; ++t) IN[t][tid] = emb[(int64_t)TOK[t] * H + tid];
  __syncthreads();

  float acc[4][4], sum[4][4];

  // h0 = proj_W @ emb + proj_b
  MATVEC(proj_W, IN, acc);
#pragma unroll
  for (int j = 0; j < 4; ++j) {
    const int hj = hg + 64 * j;
    const float pb = proj_b[hj];
#pragma unroll
    for (int tt = 0; tt < 4; ++tt) {
      const float h0v = acc[j][tt] + pb;
      H0[tg * 4 + tt][hj] = h0v;
      sum[j][tt] = h0v;
    }
  }
  __syncthreads();

  // depth-0 policy
  MATVEC(pol_W1, H0, acc);
#pragma unroll
  for (int j = 0; j < 4; ++j) {
    const int hj = hg + 64 * j;
    const float pb1 = pol_b1[hj], de0 = depth_emb[hj], w2 = pol_w2[hj];
#pragma unroll
    for (int tt = 0; tt < 4; ++tt) {
      const float z = tanhf(acc[j][tt] + pb1 + de0);
      ZW[tg * 4 + tt][hj] = z * w2;
    }
  }
  __syncthreads();
  REDUCE_TO_X(0);
  __syncthreads();

  // depth-0 children base
  MATVEC(child_W, H0, acc);
#pragma unroll
  for (int j = 0; j < 4; ++j) {
    const int hj = hg + 64 * j;
    const float cb = child_b[hj];
#pragma unroll
    for (int tt = 0; tt < 4; ++tt) {
      const float base0 = tanhf(acc[j][tt] + cb);
      B0s[tg * 4 + tt][hj] = base0;
      const float g0 = (X[0][tg * 4 + tt] >= 0.f) ? 1.f : 0.f;
      sum[j][tt] += g0 * (2.f * base0 + sibs[j]);
    }
  }
  __syncthreads();

  // depth-1 policy: polW@base (+ precomputed polW@sib_k)
  float accP[4][4];
  MATVEC(pol_W1, B0s, accP);
#pragma unroll
  for (int k = 0; k < 2; ++k) {
#pragma unroll
    for (int j = 0; j < 4; ++j) {
      const int hj = hg + 64 * j;
      const float pb1 = pol_b1[hj], de1 = depth_emb[H + hj], w2 = pol_w2[hj];
      const float ps = sibproj[k * H + hj];
#pragma unroll
      for (int tt = 0; tt < 4; ++tt) {
        const float z = tanhf(accP[j][tt] + SIB * ps + pb1 + de1);
        ZW[tg * 4 + tt][hj] = z * w2;
      }
    }
    __syncthreads();
    if (k == 0) REDUCE_TO_X(1); else REDUCE_TO_X(2);
    __syncthreads();
  }

  // depth-1 children base + final pooled
  MATVEC(child_W, B0s, acc);
#pragma unroll
  for (int j = 0; j < 4; ++j) {
    const int hj = hg + 64 * j;
    const float cb = child_b[hj];
    const float cs0 = sibproj[2 * H + hj], cs1 = sibproj[3 * H + hj];
#pragma unroll
    for (int tt = 0; tt < 4; ++tt) {
      const int t = tg * 4 + tt;
      const float g0 = (X[0][t] >= 0.f) ? 1.f : 0.f;
      const float m0 = (g0 > 0.f && X[1][t] >= 0.f) ? 1.f : 0.f;
      const float m1 = (g0 > 0.f && X[2][t] >= 0.f) ? 1.f : 0.f;
      const float bk0 = tanhf(acc[j][tt] + SIB * cs0 + cb);
      const float bk1 = tanhf(acc[j][tt] + SIB * cs1 + cb);
      float s = sum[j][tt] + m0 * (2.f * bk0 + sibs[j]) + m1 * (2.f * bk1 + sibs[j]);
      const float cnt = 1.f + 2.f * g0 + 2.f * (m0 + m1);
      const float pooled = s / (cnt + 1e-8f);
      union { _Float16 hh[2]; uint32_t u; } pk;
      pk.hh[0] = (_Float16)pooled;
      pk.hh[1] = (_Float16)(pooled * 0.015625f);  // matches 64x-scaled lo plane
      *(uint32_t*)(A2 + (int64_t)(t0 + t) * K2 + 2 * hj) = pk.u;
    }
  }
}

// ---------------- big GEMM: C[4096][50257] = A2[4096][512] * B2[50304][512]^T + out_b
// 128x128 tile, BK=64, double-buffered LDS, 2-phase pipeline (stage t+1 before
// compute t, one barrier/iter). T2 swizzle: LDS granule (row,q) holds global
// granule q^(row&7) via pre-swizzled global source; reads XOR back.
// Epilogue: acc -> LDS transpose -> contiguous 256B/instr nontemporal stores.
__global__ __launch_bounds__(256) void k_gemm(const _Float16* __restrict__ A2,
                                              const _Float16* __restrict__ B2,
                                              const float* __restrict__ out_b,
                                              float* __restrict__ C) {
  __shared__ __align__(16) char smem[65536];  // 2 x (At 16KB + Bt 16KB)
  const int tid = threadIdx.x;
  const int lane = tid & 63;
  const int w = tid >> 6;
  // bijective XCD chunking: 12576 = 8*1572, idx n-outer / m-inner
  const int wg = blockIdx.x;
  const int idx = (wg & 7) * 1572 + (wg >> 3);
  const int m0 = (idx & 31) * 128;
  const int n0 = (idx >> 5) * 128;
  f32x4 acc[4][4] = {};

  // staging geometry: per instr a wave writes 8 rows x 64 f16 (1KB linear).
  const int rl = lane >> 3;                 // row within 8-row group
  const int gsw = (lane & 7) ^ rl;          // pre-swizzled source granule
  const _Float16* gA = A2 + (int64_t)(m0 + w * 32 + rl) * K2 + gsw * 8;
  const _Float16* gB = B2 + (int64_t)(n0 + w * 32 + rl) * K2 + gsw * 8;

  const int fr = lane & 15;
  const int g = lane >> 4;                  // K-octet within 32-wide MFMA K
  const int am = (w >> 1) * 64;
  const int bn = (w & 1) * 64;

#define STAGE(c, t)                                                          \
  do {                                                                       \
    _Pragma("unroll") for (int q = 0; q < 4; ++q) {                          \
      gload_lds16(gA + (int64_t)q * 8 * K2 + (t) * 64,                       \
                  (_Float16*)(smem + (c) * 32768) + (w * 32 + q * 8) * 64);  \
      gload_lds16(gB + (int64_t)q * 8 * K2 + (t) * 64,                       \
                  (_Float16*)(smem + (c) * 32768 + 16384) +                  \
                      (w * 32 + q * 8) * 64);                                \
    }                                                                        \
  } while (0)

  STAGE(0, 0);
  __syncthreads();

  for (int t = 0; t < 8; ++t) {
    const int cur = t & 1;
    if (t < 7) STAGE(cur ^ 1, t + 1);
    const _Float16* At = (const _Float16*)(smem + cur * 32768);
    const _Float16* Bt = (const _Float16*)(smem + cur * 32768 + 16384);
#pragma unroll
    for (int kk = 0; kk < 2; ++kk) {
      f16x8 af[4], bf[4];
#pragma unroll
      for (int i = 0; i < 4; ++i)
        af[i] = *(const f16x8*)(At + (am + i * 16 + fr) * 64 +
                                (((kk * 4 + g) ^ (fr & 7)) * 8));
#pragma unroll
      for (int i = 0; i < 4; ++i)
        bf[i] = *(const f16x8*)(Bt + (bn + i * 16 + fr) * 64 +
                                (((kk * 4 + g) ^ (fr & 7)) * 8));
#pragma unroll
      for (int i = 0; i < 4; ++i)
#pragma unroll
        for (int j = 0; j < 4; ++j)
          acc[i][j] = __builtin_amdgcn_mfma_f32_16x16x32_f16(af[i], bf[j], acc[i][j], 0, 0, 0);
    }
    __syncthreads();
  }

  // ---- epilogue: per m-chunk q, transpose 32x128 f32 through LDS, stream out
  float biasj[4];
#pragma unroll
  for (int j = 0; j < 4; ++j) {
    const int gn = n0 + bn + j * 16 + fr;
    biasj[j] = (gn < VOCAB) ? out_b[gn] : 0.f;
  }
  float* L = (float*)smem;  // [32][132] padded
#pragma unroll
  for (int q = 0; q < 4; ++q) {
#pragma unroll
    for (int j = 0; j < 4; ++j) {
      const int lcol = bn + j * 16 + fr;
#pragma unroll
      for (int r = 0; r < 4; ++r) {
        const int lrow = (w >> 1) * 16 + g * 4 + r;
        L[lrow * 132 + lcol] = acc[q][j][r] + biasj[j];
      }
    }
    __syncthreads();
#pragma unroll
    for (int r8 = 0; r8 < 8; ++r8) {
      const int lr = w * 8 + r8;
      const int gm = m0 + (lr >> 4) * 64 + q * 16 + (lr & 15);
      float* Crow = C + (int64_t)gm * VOCAB + n0;
#pragma unroll
      for (int hh = 0; hh < 2; ++hh) {
        const int c = hh * 64 + lane;
        const float v = L[lr * 132 + c];
        if (n0 + c < VOCAB) __builtin_nontemporal_store(v, Crow + c);
      }
    }
    __syncthreads();
  }
#undef STAGE
}

extern "C" void kernel_launch(void* const* d_in, const int* in_sizes, int n_in,
                              void* d_out, int out_size, void* d_ws, size_t ws_size,
                              hipStream_t stream) {
  const int* tokens = (const int*)d_in[0];
  const float* embedding = (const float*)d_in[1];
  const float* proj_W = (const float*)d_in[2];
  const float* proj_b = (const float*)d_in[3];
  const float* child_W = (const float*)d_in[4];
  const float* child_b = (const float*)d_in[5];
  const float* sib_emb = (const float*)d_in[6];
  const float* depth_emb = (const float*)d_in[7];
  const float* pol_W1 = (const float*)d_in[8];
  const float* pol_b1 = (const float*)d_in[9];
  const float* pol_w2 = (const float*)d_in[10];
  const float* pol_b2 = (const float*)d_in[11];
  const float* out_W = (const float*)d_in[12];
  const float* out_b = (const float*)d_in[13];
  float* C = (float*)d_out;
  char* ws = (char*)d_ws;
  _Float16* B2 = (_Float16*)ws;                              // 50304*512*2 = 51,511,296 B
  _Float16* A2 = (_Float16*)(ws + 51511296);                 // 4096*512*2  =  4,194,304 B
  float* sibproj = (float*)(ws + 51511296 + 4194304);        // 4*256*4 = 4 KB

  k_sib<<<4, 256, 0, stream>>>(pol_W1, child_W, sib_emb, sibproj);
  k_conv<<<2048, 256, 0, stream>>>(out_W, B2);
  k_pooled<<<256, 256, 0, stream>>>(tokens, embedding, proj_W, proj_b, child_W,
                                    child_b, sib_emb, depth_emb, pol_W1, pol_b1,
                                    pol_w2, pol_b2, sibproj, A2);
  k_gemm<<<12576, 256, 0, stream>>>(A2, B2, out_b, C);
}

// Round 5
// 557.869 us; speedup vs baseline: 1.3604x; 1.1836x over previous
//
#include <hip/hip_runtime.h>
#include <stdint.h>

#define VOCAB 50257
#define NP    50304      // padded vocab = 393*128
#define H     256
#define BS    4096       // B*S tokens
#define K2    512        // hi/lo interleaved K
#define SIB   0.0625f    // 1/sqrt(256)

typedef __attribute__((ext_vector_type(8))) _Float16 f16x8;
typedef __attribute__((ext_vector_type(4))) float f32x4;

__device__ __forceinline__ void gload_lds16(const void* g, void* l) {
  __builtin_amdgcn_global_load_lds(
      (const __attribute__((address_space(1))) void*)g,
      (__attribute__((address_space(3))) void*)l, 16, 0, 0);
}

// ---------------- sib projections: polW@sib0, polW@sib1, childW@sib0, childW@sib1
__global__ __launch_bounds__(256) void k_sib(const float* __restrict__ pol_W1,
                                             const float* __restrict__ child_W,
                                             const float* __restrict__ sib_emb,
                                             float* __restrict__ sibproj) {
  const int b = blockIdx.x;  // 0..3
  const float* Wm = (b < 2) ? pol_W1 : child_W;
  const float* v = sib_emb + (b & 1) * H;
  const int h = threadIdx.x;
  const float4* wr = (const float4*)(Wm + h * H);
  const float4* vr = (const float4*)v;
  float acc = 0.f;
  for (int i = 0; i < 64; ++i) {
    float4 w = wr[i], x = vr[i];
    acc += w.x * x.x + w.y * x.y + w.z * x.z + w.w * x.w;
  }
  sibproj[b * H + h] = acc;
}

// ---------------- out_W f32 -> interleaved f16 hi/lo (lo pre-scaled by 64)
__global__ __launch_bounds__(256) void k_conv(const float* __restrict__ W,
                                              _Float16* __restrict__ B2) {
  const int64_t nit = (int64_t)NP * 64;
  for (int64_t i = (int64_t)blockIdx.x * blockDim.x + threadIdx.x; i < nit;
       i += (int64_t)gridDim.x * blockDim.x) {
    const int v = (int)(i >> 6);
    const int h4 = ((int)i & 63) * 4;
    float4 w;
    if (v < VOCAB) w = *(const float4*)(W + (int64_t)v * H + h4);
    else w = make_float4(0.f, 0.f, 0.f, 0.f);
    float a[4] = {w.x, w.y, w.z, w.w};
    _Float16 o[8];
#pragma unroll
    for (int j = 0; j < 4; ++j) {
      _Float16 hi = (_Float16)a[j];
      float lo = (a[j] - (float)hi) * 64.f;
      o[2 * j] = hi;
      o[2 * j + 1] = (_Float16)lo;
    }
    *(f16x8*)(B2 + (int64_t)v * K2 + h4 * 2) = *(f16x8*)o;
  }
}

// ---------------- per-token tree -> pooled -> A2 (f16, dup columns: [a, a/64])
#define MATVEC(Wp, SRC, ACC)                                                      \
  do {                                                                            \
    _Pragma("unroll") for (int j = 0; j < 4; ++j)                                 \
        _Pragma("unroll") for (int tt = 0; tt < 4; ++tt) ACC[j][tt] = 0.f;        \
    _Pragma("unroll 2") for (int e4 = 0; e4 < 64; ++e4) {                         \
      float4 wv[4], sv[4];                                                        \
      _Pragma("unroll") for (int j = 0; j < 4; ++j)                               \
          wv[j] = *(const float4*)(Wp + (hg + 64 * j) * H + e4 * 4);              \
      _Pragma("unroll") for (int tt = 0; tt < 4; ++tt)                            \
          sv[tt] = *(const float4*)&SRC[tg * 4 + tt][e4 * 4];                     \
      _Pragma("unroll") for (int j = 0; j < 4; ++j)                               \
          _Pragma("unroll") for (int tt = 0; tt < 4; ++tt)                        \
              ACC[j][tt] += wv[j].x * sv[tt].x + wv[j].y * sv[tt].y +             \
                            wv[j].z * sv[tt].z + wv[j].w * sv[tt].w;              \
    }                                                                             \
  } while (0)

#define REDUCE_TO_X(slot)                                                \
  do {                                                                   \
    const int rt = tid >> 4, rl = tid & 15;                              \
    float part = 0.f;                                                    \
    _Pragma("unroll") for (int i = 0; i < 16; ++i) part +=               \
        ZW[rt][rl + 16 * i];                                             \
    part += __shfl_xor(part, 1, 16);                                     \
    part += __shfl_xor(part, 2, 16);                                     \
    part += __shfl_xor(part, 4, 16);                                     \
    part += __shfl_xor(part, 8, 16);                                     \
    if (rl == 0) X[slot][rt] = part + b2;                                \
  } while (0)

__global__ __launch_bounds__(256) void k_pooled(
    const int* __restrict__ tokens, const float* __restrict__ emb,
    const float* __restrict__ proj_W, const float* __restrict__ proj_b,
    const float* __restrict__ child_W, const float* __restrict__ child_b,
    const float* __restrict__ sib_emb, const float* __restrict__ depth_emb,
    const float* __restrict__ pol_W1, const float* __restrict__ pol_b1,
    const float* __restrict__ pol_w2, const float* __restrict__ pol_b2,
    const float* __restrict__ sibproj, _Float16* __restrict__ A2) {
  __shared__ float IN[16][256];
  __shared__ float H0[16][256];
  __shared__ float B0s[16][256];
  __shared__ float ZW[16][264];
  __shared__ float X[3][16];
  __shared__ int TOK[16];
  const int tid = threadIdx.x;
  const int hg = tid & 63;   // h = hg + 64*j
  const int tg = tid >> 6;   // tokens tg*4 .. tg*4+3
  const int t0 = blockIdx.x * 16;
  const float b2 = pol_b2[0];

  float sibs[4];
#pragma unroll
  for (int j = 0; j < 4; ++j) {
    const int hj = hg + 64 * j;
    sibs[j] = SIB * (sib_emb[hj] + sib_emb[H + hj]);
  }

  if (tid < 16) TOK[tid] = tokens[t0 + tid];
  __syncthreads();
  for (int t = 0; t < 16; ++t) IN[t][tid] = emb[(int64_t)TOK[t] * H + tid];
  __syncthreads();

  float acc[4][4], sum[4][4];

  // h0 = proj_W @ emb + proj_b
  MATVEC(proj_W, IN, acc);
#pragma unroll
  for (int j = 0; j < 4; ++j) {
    const int hj = hg + 64 * j;
    const float pb = proj_b[hj];
#pragma unroll
    for (int tt = 0; tt < 4; ++tt) {
      const float h0v = acc[j][tt] + pb;
      H0[tg * 4 + tt][hj] = h0v;
      sum[j][tt] = h0v;
    }
  }
  __syncthreads();

  // depth-0 policy
  MATVEC(pol_W1, H0, acc);
#pragma unroll
  for (int j = 0; j < 4; ++j) {
    const int hj = hg + 64 * j;
    const float pb1 = pol_b1[hj], de0 = depth_emb[hj], w2 = pol_w2[hj];
#pragma unroll
    for (int tt = 0; tt < 4; ++tt) {
      const float z = tanhf(acc[j][tt] + pb1 + de0);
      ZW[tg * 4 + tt][hj] = z * w2;
    }
  }
  __syncthreads();
  REDUCE_TO_X(0);
  __syncthreads();

  // depth-0 children base
  MATVEC(child_W, H0, acc);
#pragma unroll
  for (int j = 0; j < 4; ++j) {
    const int hj = hg + 64 * j;
    const float cb = child_b[hj];
#pragma unroll
    for (int tt = 0; tt < 4; ++tt) {
      const float base0 = tanhf(acc[j][tt] + cb);
      B0s[tg * 4 + tt][hj] = base0;
      const float g0 = (X[0][tg * 4 + tt] >= 0.f) ? 1.f : 0.f;
      sum[j][tt] += g0 * (2.f * base0 + sibs[j]);
    }
  }
  __syncthreads();

  // depth-1 policy: polW@base (+ precomputed polW@sib_k)
  float accP[4][4];
  MATVEC(pol_W1, B0s, accP);
#pragma unroll
  for (int k = 0; k < 2; ++k) {
#pragma unroll
    for (int j = 0; j < 4; ++j) {
      const int hj = hg + 64 * j;
      const float pb1 = pol_b1[hj], de1 = depth_emb[H + hj], w2 = pol_w2[hj];
      const float ps = sibproj[k * H + hj];
#pragma unroll
      for (int tt = 0; tt < 4; ++tt) {
        const float z = tanhf(accP[j][tt] + SIB * ps + pb1 + de1);
        ZW[tg * 4 + tt][hj] = z * w2;
      }
    }
    __syncthreads();
    if (k == 0) REDUCE_TO_X(1); else REDUCE_TO_X(2);
    __syncthreads();
  }

  // depth-1 children base + final pooled
  MATVEC(child_W, B0s, acc);
#pragma unroll
  for (int j = 0; j < 4; ++j) {
    const int hj = hg + 64 * j;
    const float cb = child_b[hj];
    const float cs0 = sibproj[2 * H + hj], cs1 = sibproj[3 * H + hj];
#pragma unroll
    for (int tt = 0; tt < 4; ++tt) {
      const int t = tg * 4 + tt;
      const float g0 = (X[0][t] >= 0.f) ? 1.f : 0.f;
      const float m0 = (g0 > 0.f && X[1][t] >= 0.f) ? 1.f : 0.f;
      const float m1 = (g0 > 0.f && X[2][t] >= 0.f) ? 1.f : 0.f;
      const float bk0 = tanhf(acc[j][tt] + SIB * cs0 + cb);
      const float bk1 = tanhf(acc[j][tt] + SIB * cs1 + cb);
      float s = sum[j][tt] + m0 * (2.f * bk0 + sibs[j]) + m1 * (2.f * bk1 + sibs[j]);
      const float cnt = 1.f + 2.f * g0 + 2.f * (m0 + m1);
      const float pooled = s / (cnt + 1e-8f);
      union { _Float16 hh[2]; uint32_t u; } pk;
      pk.hh[0] = (_Float16)pooled;
      pk.hh[1] = (_Float16)(pooled * 0.015625f);  // matches 64x-scaled lo plane
      *(uint32_t*)(A2 + (int64_t)(t0 + t) * K2 + 2 * hj) = pk.u;
    }
  }
}

// ---------------- big GEMM: C[4096][50257] = A2[4096][512] * B2[50304][512]^T + out_b
// 128x128 tile, BK=64, double-buffered LDS, counted-vmcnt 2-phase pipeline:
// STAGE(t+1) -> vmcnt(8) [only stage(t) drained] -> barrier -> compute -> barrier.
// Next-tile loads stay in flight across both barriers (no vmcnt(0) drain).
// Within-XCD m-chunk-16 ordering keeps the A-chunk (2MB) L2-resident.
// Epilogue: acc -> LDS transpose -> contiguous 256B nontemporal stores.
__global__ __launch_bounds__(256) void k_gemm(const _Float16* __restrict__ A2,
                                              const _Float16* __restrict__ B2,
                                              const float* __restrict__ out_b,
                                              float* __restrict__ C) {
  __shared__ __align__(16) char smem[65536];  // 2 x (At 16KB + Bt 16KB)
  const int tid = threadIdx.x;
  const int lane = tid & 63;
  const int w = tid >> 6;
  // XCD chunking (12576 = 8*1572) + within-XCD bijective m-chunk-16 reorder:
  // local < 1568 (=2*16*49): (mhalf, n_l, m_in); tail 4 blocks map identity.
  const int wg = blockIdx.x;
  const int xcd = wg & 7;
  const int local = wg >> 3;  // [0,1572)
  int gl;
  if (local < 1568) {
    const int mhalf = local / 784;  // 784 = 16*49
    const int r = local % 784;
    const int n_l = r >> 4;   // 0..48
    const int m_in = r & 15;
    gl = n_l * 32 + mhalf * 16 + m_in;
  } else {
    gl = local;
  }
  const int idx = xcd * 1572 + gl;
  const int m0 = (idx & 31) * 128;
  const int n0 = (idx >> 5) * 128;
  f32x4 acc[4][4] = {};

  // staging geometry: per instr a wave writes 8 rows x 64 f16 (1KB linear).
  const int rl = lane >> 3;                 // row within 8-row group
  const int gsw = (lane & 7) ^ rl;          // pre-swizzled source granule
  const _Float16* gA = A2 + (int64_t)(m0 + w * 32 + rl) * K2 + gsw * 8;
  const _Float16* gB = B2 + (int64_t)(n0 + w * 32 + rl) * K2 + gsw * 8;

  const int fr = lane & 15;
  const int g = lane >> 4;                  // K-octet within 32-wide MFMA K
  const int am = (w >> 1) * 64;
  const int bn = (w & 1) * 64;

#define STAGE(c, t)                                                          \
  do {                                                                       \
    _Pragma("unroll") for (int q = 0; q < 4; ++q) {                          \
      gload_lds16(gA + (int64_t)q * 8 * K2 + (t) * 64,                       \
                  (_Float16*)(smem + (c) * 32768) + (w * 32 + q * 8) * 64);  \
      gload_lds16(gB + (int64_t)q * 8 * K2 + (t) * 64,                       \
                  (_Float16*)(smem + (c) * 32768 + 16384) +                  \
                      (w * 32 + q * 8) * 64);                                \
    }                                                                        \
  } while (0)

  STAGE(0, 0);  // 8 loads/thread outstanding

  for (int t = 0; t < 8; ++t) {
    const int cur = t & 1;
    if (t < 7) {
      STAGE(cur ^ 1, t + 1);  // +8 -> 16 outstanding
      asm volatile("s_waitcnt vmcnt(8)" ::: "memory");  // stage(t) complete
    } else {
      asm volatile("s_waitcnt vmcnt(0)" ::: "memory");
    }
    __builtin_amdgcn_s_barrier();          // all waves' stage(t) visible
    __builtin_amdgcn_sched_barrier(0);
    const _Float16* At = (const _Float16*)(smem + cur * 32768);
    const _Float16* Bt = (const _Float16*)(smem + cur * 32768 + 16384);
#pragma unroll
    for (int kk = 0; kk < 2; ++kk) {
      f16x8 af[4], bf[4];
#pragma unroll
      for (int i = 0; i < 4; ++i)
        af[i] = *(const f16x8*)(At + (am + i * 16 + fr) * 64 +
                                (((kk * 4 + g) ^ (fr & 7)) * 8));
#pragma unroll
      for (int i = 0; i < 4; ++i)
        bf[i] = *(const f16x8*)(Bt + (bn + i * 16 + fr) * 64 +
                                (((kk * 4 + g) ^ (fr & 7)) * 8));
#pragma unroll
      for (int i = 0; i < 4; ++i)
#pragma unroll
        for (int j = 0; j < 4; ++j)
          acc[i][j] = __builtin_amdgcn_mfma_f32_16x16x32_f16(af[i], bf[j], acc[i][j], 0, 0, 0);
    }
    __builtin_amdgcn_sched_barrier(0);
    __builtin_amdgcn_s_barrier();          // reads of buf[cur] done -> safe to overwrite
  }

  // ---- epilogue: per m-chunk q, transpose 32x128 f32 through LDS, stream out
  float biasj[4];
#pragma unroll
  for (int j = 0; j < 4; ++j) {
    const int gn = n0 + bn + j * 16 + fr;
    biasj[j] = (gn < VOCAB) ? out_b[gn] : 0.f;
  }
  float* L = (float*)smem;  // [32][132] padded
#pragma unroll
  for (int q = 0; q < 4; ++q) {
#pragma unroll
    for (int j = 0; j < 4; ++j) {
      const int lcol = bn + j * 16 + fr;
#pragma unroll
      for (int r = 0; r < 4; ++r) {
        const int lrow = (w >> 1) * 16 + g * 4 + r;
        L[lrow * 132 + lcol] = acc[q][j][r] + biasj[j];
      }
    }
    __syncthreads();
#pragma unroll
    for (int r8 = 0; r8 < 8; ++r8) {
      const int lr = w * 8 + r8;
      const int gm = m0 + (lr >> 4) * 64 + q * 16 + (lr & 15);
      float* Crow = C + (int64_t)gm * VOCAB + n0;
#pragma unroll
      for (int hh = 0; hh < 2; ++hh) {
        const int c = hh * 64 + lane;
        const float v = L[lr * 132 + c];
        if (n0 + c < VOCAB) __builtin_nontemporal_store(v, Crow + c);
      }
    }
    __syncthreads();
  }
#undef STAGE
}

extern "C" void kernel_launch(void* const* d_in, const int* in_sizes, int n_in,
                              void* d_out, int out_size, void* d_ws, size_t ws_size,
                              hipStream_t stream) {
  const int* tokens = (const int*)d_in[0];
  const float* embedding = (const float*)d_in[1];
  const float* proj_W = (const float*)d_in[2];
  const float* proj_b = (const float*)d_in[3];
  const float* child_W = (const float*)d_in[4];
  const float* child_b = (const float*)d_in[5];
  const float* sib_emb = (const float*)d_in[6];
  const float* depth_emb = (const float*)d_in[7];
  const float* pol_W1 = (const float*)d_in[8];
  const float* pol_b1 = (const float*)d_in[9];
  const float* pol_w2 = (const float*)d_in[10];
  const float* pol_b2 = (const float*)d_in[11];
  const float* out_W = (const float*)d_in[12];
  const float* out_b = (const float*)d_in[13];
  float* C = (float*)d_out;
  char* ws = (char*)d_ws;
  _Float16* B2 = (_Float16*)ws;                              // 50304*512*2 = 51,511,296 B
  _Float16* A2 = (_Float16*)(ws + 51511296);                 // 4096*512*2  =  4,194,304 B
  float* sibproj = (float*)(ws + 51511296 + 4194304);        // 4*256*4 = 4 KB

  k_sib<<<4, 256, 0, stream>>>(pol_W1, child_W, sib_emb, sibproj);
  k_conv<<<2048, 256, 0, stream>>>(out_W, B2);
  k_pooled<<<256, 256, 0, stream>>>(tokens, embedding, proj_W, proj_b, child_W,
                                    child_b, sib_emb, depth_emb, pol_W1, pol_b1,
                                    pol_w2, pol_b2, sibproj, A2);
  k_gemm<<<12576, 256, 0, stream>>>(A2, B2, out_b, C);
}